// Round 1
// baseline (38340.149 us; speedup 1.0000x reference)
//
#include <hip/hip_runtime.h>

typedef unsigned short u16;
typedef __attribute__((ext_vector_type(8))) short short8;
typedef __attribute__((ext_vector_type(4))) float f32x4;

#define DEVINL __device__ __forceinline__

constexpr int Nb = 64;     // batch
constexpr int Tt = 1024;   // time
constexpr int Dd = 1024;   // input dim
constexpr int Hh = 1024;   // hidden
constexpr int NWG = 256;   // workgroups (== CUs)
constexpr int TPB = 256;   // threads per wg (4 waves)
constexpr int NH = Nb * Hh; // 65536

struct GBar { unsigned cnt; unsigned gen; };

DEVINL u16 f2b(float f) {
  union { float f; unsigned u; } v; v.f = f;
  unsigned r = (v.u + 0x7fffu + ((v.u >> 16) & 1u)) >> 16;
  return (u16)r;
}
DEVINL float sigm(float x) { return 1.f / (1.f + __expf(-x)); }
DEVINL float tanhfast(float x) { float e = __expf(2.f * x); return 1.f - 2.f / (e + 1.f); }

// Sense-reversing grid barrier. __syncthreads drains vmcnt (stores in L2);
// thread0's ACQ_REL agent-scope atomic does the L2 wb/inv; winner bumps gen
// with RELEASE after resetting cnt.
DEVINL void grid_barrier(GBar* b, unsigned nwg) {
  __syncthreads();
  if (threadIdx.x == 0) {
    unsigned g = __hip_atomic_load(&b->gen, __ATOMIC_RELAXED, __HIP_MEMORY_SCOPE_AGENT);
    unsigned a = __hip_atomic_fetch_add(&b->cnt, 1u, __ATOMIC_ACQ_REL, __HIP_MEMORY_SCOPE_AGENT);
    if (a == nwg - 1u) {
      __hip_atomic_store(&b->cnt, 0u, __ATOMIC_RELAXED, __HIP_MEMORY_SCOPE_AGENT);
      __hip_atomic_fetch_add(&b->gen, 1u, __ATOMIC_RELEASE, __HIP_MEMORY_SCOPE_AGENT);
    } else {
      while (__hip_atomic_load(&b->gen, __ATOMIC_ACQUIRE, __HIP_MEMORY_SCOPE_AGENT) == g) {
        __builtin_amdgcn_s_sleep(2);
      }
    }
  }
  __syncthreads();
}

__global__ void cvt_x_kernel(const float* __restrict__ x, u16* __restrict__ xb) {
  size_t i = ((size_t)blockIdx.x * TPB + threadIdx.x) * 8;
  float4 a = *reinterpret_cast<const float4*>(x + i);
  float4 b = *reinterpret_cast<const float4*>(x + i + 4);
  short8 r;
  r[0] = (short)f2b(a.x); r[1] = (short)f2b(a.y);
  r[2] = (short)f2b(a.z); r[3] = (short)f2b(a.w);
  r[4] = (short)f2b(b.x); r[5] = (short)f2b(b.y);
  r[6] = (short)f2b(b.z); r[7] = (short)f2b(b.w);
  *reinterpret_cast<short8*>(xb + i) = r;
}

// Persistent LSTM kernel. wg g owns 4 h-columns (16 preact columns, gates
// interleaved c = gate*4+q). Weight slice [2048][16] lives in LDS (bf16,
// XOR-swizzled). One grid barrier per timestep; h ping-pongs in ws as bf16.
template<bool XBF16>
__global__ __launch_bounds__(TPB, 1) void lstm_persist(
    const float* __restrict__ x, const u16* __restrict__ xb,
    const float* __restrict__ h0, const float* __restrict__ Wx,
    const float* __restrict__ Wh, const float* __restrict__ bias,
    float* __restrict__ out, u16* __restrict__ hbuf, GBar* bar)
{
  __shared__ u16 Bt[16][2048];     // 64 KiB, [c][k ^ ((c&7)<<3)]
  __shared__ float ex[4][16][20];  // per-wave preact exchange, padded

  const int g   = blockIdx.x;
  const int tid = threadIdx.x;
  const int w   = tid >> 6;
  const int l   = tid & 63;

  // Column remap: the 8 wgs sharing a 128B output line land on one XCD.
  const int j0 = (int)(((((unsigned)g & 7u) << 5) + ((unsigned)g >> 3)) << 2);

  // ---- one-time: load [Wh;Wx] column slice -> LDS bf16, swizzled ----
  for (int idx = tid; idx < 16 * 2048; idx += TPB) {
    int k = idx >> 4;
    int c = idx & 15;
    int pc = (c >> 2) * 1024 + j0 + (c & 3);
    float v = (k < 1024) ? Wh[(size_t)k * 4096 + pc]
                         : Wx[(size_t)(k - 1024) * 4096 + pc];
    Bt[c][k ^ ((c & 7) << 3)] = f2b(v);
  }

  // ---- one-time: h0 -> hbuf[0] (bf16); grid has exactly N*H threads ----
  {
    int gid = g * TPB + tid;
    hbuf[gid] = f2b(h0[gid]);
  }

  // gate-stage lane roles: lane -> (row ro=l>>2, h-col offset qb=l&3)
  const int qb = l & 3;
  const float bI = bias[0 * 1024 + j0 + qb];
  const float bF = bias[1 * 1024 + j0 + qb];
  const float bO = bias[2 * 1024 + j0 + qb];
  const float bG = bias[3 * 1024 + j0 + qb];

  // MFMA lane roles (A: m=l&15, 8 contiguous k at 8*(l>>4); B symmetric)
  const int arow = l & 15;
  const int kg   = (l >> 4) * 8;
  const int bswz = (l & 7) << 3;
  const u16* btrow = &Bt[l & 15][0];

  float c_reg = 0.f;

  grid_barrier(bar, NWG);

  for (int t = 0; t < Tt; ++t) {
    const u16* hb  = hbuf + (t & 1) * NH;
    u16*       hbn = hbuf + ((t + 1) & 1) * NH;

    f32x4 acc = {0.f, 0.f, 0.f, 0.f};
    const int nrow = 16 * w + arow;
    const u16* hrow = hb + (size_t)nrow * Hh + kg;

    #pragma unroll 8
    for (int kk = 0; kk < 1024; kk += 32) {
      short8 av = *reinterpret_cast<const short8*>(hrow + kk);
      short8 bv = *reinterpret_cast<const short8*>(btrow + ((kk + kg) ^ bswz));
      acc = __builtin_amdgcn_mfma_f32_16x16x32_bf16(av, bv, acc, 0, 0, 0);
    }
    if constexpr (XBF16) {
      const u16* xrow = xb + ((size_t)nrow * Tt + t) * Dd + kg;
      #pragma unroll 8
      for (int kk = 0; kk < 1024; kk += 32) {
        short8 av = *reinterpret_cast<const short8*>(xrow + kk);
        short8 bv = *reinterpret_cast<const short8*>(btrow + ((1024 + kk + kg) ^ bswz));
        acc = __builtin_amdgcn_mfma_f32_16x16x32_bf16(av, bv, acc, 0, 0, 0);
      }
    } else {
      const float* xrow = x + ((size_t)nrow * Tt + t) * Dd + kg;
      #pragma unroll 4
      for (int kk = 0; kk < 1024; kk += 32) {
        float4 xa = *reinterpret_cast<const float4*>(xrow + kk);
        float4 xc = *reinterpret_cast<const float4*>(xrow + kk + 4);
        short8 av;
        av[0] = (short)f2b(xa.x); av[1] = (short)f2b(xa.y);
        av[2] = (short)f2b(xa.z); av[3] = (short)f2b(xa.w);
        av[4] = (short)f2b(xc.x); av[5] = (short)f2b(xc.y);
        av[6] = (short)f2b(xc.z); av[7] = (short)f2b(xc.w);
        short8 bv = *reinterpret_cast<const short8*>(btrow + ((1024 + kk + kg) ^ bswz));
        acc = __builtin_amdgcn_mfma_f32_16x16x32_bf16(av, bv, acc, 0, 0, 0);
      }
    }

    // exchange preact tile within the wave's LDS scratch
    ex[w][(l >> 4) * 4 + 0][l & 15] = acc[0];
    ex[w][(l >> 4) * 4 + 1][l & 15] = acc[1];
    ex[w][(l >> 4) * 4 + 2][l & 15] = acc[2];
    ex[w][(l >> 4) * 4 + 3][l & 15] = acc[3];
    __syncthreads();

    const int ro = l >> 2;
    const float ai = ex[w][ro][0  + qb] + bI;
    const float af = ex[w][ro][4  + qb] + bF;
    const float ao = ex[w][ro][8  + qb] + bO;
    const float ag = ex[w][ro][12 + qb] + bG;
    const float ig = sigm(ai), fg = sigm(af), og = sigm(ao);
    const float gg = tanhfast(ag);
    c_reg = fg * c_reg + ig * gg;
    const float hv = og * tanhfast(c_reg);

    const int no = 16 * w + ro;
    const int j  = j0 + qb;
    out[((size_t)no * Tt + t) * Hh + j] = hv;
    hbn[no * Hh + j] = f2b(hv);

    grid_barrier(bar, NWG);
  }
}

extern "C" void kernel_launch(void* const* d_in, const int* in_sizes, int n_in,
                              void* d_out, int out_size, void* d_ws, size_t ws_size,
                              hipStream_t stream) {
  const float* x    = (const float*)d_in[0];
  const float* h0   = (const float*)d_in[1];
  const float* Wx   = (const float*)d_in[2];
  const float* Wh   = (const float*)d_in[3];
  const float* bias = (const float*)d_in[4];
  float* out = (float*)d_out;

  char* wsb = (char*)d_ws;
  GBar* bar = (GBar*)wsb;                       // 256 B
  u16* hbuf = (u16*)(wsb + 256);                // 2 x 128 KiB ping-pong
  const size_t xb_off = (size_t)1 << 20;
  const size_t xb_bytes = (size_t)Nb * Tt * Dd * 2;
  u16* xb = (u16*)(wsb + xb_off);

  hipMemsetAsync(bar, 0, 256, stream);

  const bool use_xb = ws_size >= xb_off + xb_bytes;
  void* args[] = {(void*)&x, (void*)&xb, (void*)&h0, (void*)&Wx, (void*)&Wh,
                  (void*)&bias, (void*)&out, (void*)&hbuf, (void*)&bar};
  if (use_xb) {
    cvt_x_kernel<<<dim3((Nb * Tt * Dd) / (8 * TPB)), dim3(TPB), 0, stream>>>(x, xb);
    hipLaunchCooperativeKernel((const void*)lstm_persist<true>,
                               dim3(NWG), dim3(TPB), args, 0, stream);
  } else {
    hipLaunchCooperativeKernel((const void*)lstm_persist<false>,
                               dim3(NWG), dim3(TPB), args, 0, stream);
  }
}

// Round 2
// 26989.636 us; speedup vs baseline: 1.4206x; 1.4206x over previous
//
#include <hip/hip_runtime.h>

typedef unsigned short u16;
typedef __attribute__((ext_vector_type(8))) short short8;
typedef __attribute__((ext_vector_type(4))) float f32x4;

#define DEVINL __device__ __forceinline__

constexpr int Nb = 64;     // batch
constexpr int Tt = 1024;   // time
constexpr int Dd = 1024;   // input dim
constexpr int Hh = 1024;   // hidden
constexpr int NWG = 256;   // workgroups (== CUs)
constexpr int TPB = 256;   // threads per wg (4 waves)
constexpr int TWG = 128;   // wgs per team
constexpr int MS  = 32;    // samples per team

struct Flag { unsigned v; unsigned pad[31]; };  // one 128B line each

DEVINL u16 f2b(float f) {
  union { float f; unsigned u; } v; v.f = f;
  unsigned r = (v.u + 0x7fffu + ((v.u >> 16) & 1u)) >> 16;
  return (u16)r;
}
DEVINL float sigm(float x) { return 1.f / (1.f + __expf(-x)); }
DEVINL float tanhfast(float x) { float e = __expf(2.f * x); return 1.f - 2.f / (e + 1.f); }

// Team barrier: flag-array, no same-line RMWs.
// Each wg release-stores epoch to its own line; master wg (r==0) polls all
// TWG flags in parallel (128 threads), then release-stores epoch to 4
// per-XCD release lines; every wg's thread0 acquire-polls its line.
DEVINL void team_barrier(Flag* tArr, Flag* tRel, int r, int slot, int tid,
                         unsigned ep) {
  __syncthreads();  // drains vmcnt: all this wg's h/out stores issued
  if (tid == 0)
    __hip_atomic_store(&tArr[r].v, ep, __ATOMIC_RELEASE, __HIP_MEMORY_SCOPE_AGENT);
  if (r == 0) {
    if (tid < TWG) {
      while (__hip_atomic_load(&tArr[tid].v, __ATOMIC_ACQUIRE,
                               __HIP_MEMORY_SCOPE_AGENT) < ep)
        __builtin_amdgcn_s_sleep(1);
    }
    __syncthreads();
    if (tid < 4)
      __hip_atomic_store(&tRel[tid].v, ep, __ATOMIC_RELEASE, __HIP_MEMORY_SCOPE_AGENT);
  }
  if (tid == 0) {
    while (__hip_atomic_load(&tRel[slot].v, __ATOMIC_ACQUIRE,
                             __HIP_MEMORY_SCOPE_AGENT) < ep)
      __builtin_amdgcn_s_sleep(1);
  }
  __syncthreads();
}

__global__ void cvt_x_kernel(const float* __restrict__ x, u16* __restrict__ xb) {
  size_t i = ((size_t)blockIdx.x * TPB + threadIdx.x) * 8;
  float4 a = *reinterpret_cast<const float4*>(x + i);
  float4 b = *reinterpret_cast<const float4*>(x + i + 4);
  short8 r;
  r[0] = (short)f2b(a.x); r[1] = (short)f2b(a.y);
  r[2] = (short)f2b(a.z); r[3] = (short)f2b(a.w);
  r[4] = (short)f2b(b.x); r[5] = (short)f2b(b.y);
  r[6] = (short)f2b(b.z); r[7] = (short)f2b(b.w);
  *reinterpret_cast<short8*>(xb + i) = r;
}

// 2 independent teams x 128 wgs. Team handles 32 samples, wg owns 8 h-cols
// (32 preact cols, gate-major c = g*8+jj). [Wh;Wx] slice [32][2048] bf16 in
// LDS (XOR-swizzled). Waves split K: w0/w1 = h halves, w2/w3 = x halves;
// partials reduced via padded LDS exchange. One team barrier per step.
template<bool XBF16>
__global__ __launch_bounds__(TPB, 1) void lstm_team(
    const float* __restrict__ x, const u16* __restrict__ xb,
    const float* __restrict__ h0, const float* __restrict__ Wx,
    const float* __restrict__ Wh, const float* __restrict__ bias,
    float* __restrict__ out, u16* __restrict__ hbase,
    Flag* __restrict__ arr, Flag* __restrict__ rel)
{
  __shared__ u16 Bt[32][2048];       // 128 KiB, [c][k ^ ((c&7)<<3)]
  __shared__ float ex[4][32][36];    // 18.4 KiB partial-sum exchange

  const int g   = blockIdx.x;
  const int tid = threadIdx.x;
  const int w   = tid >> 6;
  const int l   = tid & 63;

  const int team = ((g & 7) < 4) ? 0 : 1;   // blockIdx%8 -> XCD heuristic
  const int r    = (g >> 3) * 4 + (g & 3);  // rank within team, 0..127
  const int slot = g & 3;                   // release-line index
  const int n0   = team * MS;
  const int jc0  = r * 8;                   // this wg's 8 h-columns

  Flag* tArr = arr + team * TWG;
  Flag* tRel = rel + team * 4;
  u16*  hb0  = hbase + (size_t)team * (2 * MS * Hh);

  // ---- one-time: [Wh;Wx] column slice -> LDS bf16, swizzled ----
  for (int idx = tid; idx < 32 * 2048; idx += TPB) {
    int k = idx >> 5;
    int c = idx & 31;
    int pc = (c >> 3) * 1024 + jc0 + (c & 7);
    float v = (k < 1024) ? Wh[(size_t)k * 4096 + pc]
                         : Wx[(size_t)(k - 1024) * 4096 + pc];
    Bt[c][k ^ ((c & 7) << 3)] = f2b(v);
  }

  // ---- one-time: h0 -> ping slot 0 (team covers exactly MS*Hh values) ----
  {
    int idx = r * TPB + tid;  // 0..32767
    hb0[idx] = f2b(h0[(size_t)n0 * Hh + idx]);
  }

  // epilogue roles: thread -> (n = tid>>3, jj = tid&7)
  const int jj = tid & 7;
  const int nE = tid >> 3;
  const float bI = bias[0 * 1024 + jc0 + jj];
  const float bF = bias[1 * 1024 + jc0 + jj];
  const float bO = bias[2 * 1024 + jc0 + jj];
  const float bG = bias[3 * 1024 + jc0 + jj];
  float c_reg = 0.f;

  // MFMA lane roles
  const int arow = l & 15;
  const int kg   = (l >> 4) * 8;
  const int kb   = w * 512;         // this wave's K-slice base (abs k)
  const int sw   = (l & 7) << 3;
  const u16* bp0 = &Bt[l & 15][0];
  const u16* bp1 = &Bt[16 | (l & 15)][0];

  team_barrier(tArr, tRel, r, slot, tid, 1u);

  for (int t = 0; t < Tt; ++t) {
    const u16* hb  = hb0 + (t & 1) * (MS * Hh);
    u16*       hbn = hb0 + ((t + 1) & 1) * (MS * Hh);

    f32x4 a00 = {0.f,0.f,0.f,0.f}, a01 = {0.f,0.f,0.f,0.f};
    f32x4 a10 = {0.f,0.f,0.f,0.f}, a11 = {0.f,0.f,0.f,0.f};

    if (w < 2) {  // h contribution, k in [kb, kb+512)
      const u16* ap = hb + (size_t)arow * Hh + kb + kg;
      #pragma unroll
      for (int kk = 0; kk < 512; kk += 32) {
        short8 av0 = *reinterpret_cast<const short8*>(ap + kk);
        short8 av1 = *reinterpret_cast<const short8*>(ap + 16 * Hh + kk);
        int ka = (kb + kg + kk) ^ sw;
        short8 bv0 = *reinterpret_cast<const short8*>(bp0 + ka);
        short8 bv1 = *reinterpret_cast<const short8*>(bp1 + ka);
        a00 = __builtin_amdgcn_mfma_f32_16x16x32_bf16(av0, bv0, a00, 0, 0, 0);
        a01 = __builtin_amdgcn_mfma_f32_16x16x32_bf16(av0, bv1, a01, 0, 0, 0);
        a10 = __builtin_amdgcn_mfma_f32_16x16x32_bf16(av1, bv0, a10, 0, 0, 0);
        a11 = __builtin_amdgcn_mfma_f32_16x16x32_bf16(av1, bv1, a11, 0, 0, 0);
      }
    } else {      // x contribution, d in [kb-1024, kb-512)
      const int d0 = kb - 1024 + kg;
      if constexpr (XBF16) {
        const u16* ap0 = xb + ((size_t)(n0 + arow)      * Tt + t) * Dd + d0;
        const u16* ap1 = xb + ((size_t)(n0 + 16 + arow) * Tt + t) * Dd + d0;
        #pragma unroll
        for (int kk = 0; kk < 512; kk += 32) {
          short8 av0 = *reinterpret_cast<const short8*>(ap0 + kk);
          short8 av1 = *reinterpret_cast<const short8*>(ap1 + kk);
          int ka = (kb + kg + kk) ^ sw;
          short8 bv0 = *reinterpret_cast<const short8*>(bp0 + ka);
          short8 bv1 = *reinterpret_cast<const short8*>(bp1 + ka);
          a00 = __builtin_amdgcn_mfma_f32_16x16x32_bf16(av0, bv0, a00, 0, 0, 0);
          a01 = __builtin_amdgcn_mfma_f32_16x16x32_bf16(av0, bv1, a01, 0, 0, 0);
          a10 = __builtin_amdgcn_mfma_f32_16x16x32_bf16(av1, bv0, a10, 0, 0, 0);
          a11 = __builtin_amdgcn_mfma_f32_16x16x32_bf16(av1, bv1, a11, 0, 0, 0);
        }
      } else {
        const float* ap0 = x + ((size_t)(n0 + arow)      * Tt + t) * Dd + d0;
        const float* ap1 = x + ((size_t)(n0 + 16 + arow) * Tt + t) * Dd + d0;
        #pragma unroll
        for (int kk = 0; kk < 512; kk += 32) {
          float4 xa = *reinterpret_cast<const float4*>(ap0 + kk);
          float4 xc = *reinterpret_cast<const float4*>(ap0 + kk + 4);
          float4 ya = *reinterpret_cast<const float4*>(ap1 + kk);
          float4 yc = *reinterpret_cast<const float4*>(ap1 + kk + 4);
          short8 av0, av1;
          av0[0]=(short)f2b(xa.x); av0[1]=(short)f2b(xa.y);
          av0[2]=(short)f2b(xa.z); av0[3]=(short)f2b(xa.w);
          av0[4]=(short)f2b(xc.x); av0[5]=(short)f2b(xc.y);
          av0[6]=(short)f2b(xc.z); av0[7]=(short)f2b(xc.w);
          av1[0]=(short)f2b(ya.x); av1[1]=(short)f2b(ya.y);
          av1[2]=(short)f2b(ya.z); av1[3]=(short)f2b(ya.w);
          av1[4]=(short)f2b(yc.x); av1[5]=(short)f2b(yc.y);
          av1[6]=(short)f2b(yc.z); av1[7]=(short)f2b(yc.w);
          int ka = (kb + kg + kk) ^ sw;
          short8 bv0 = *reinterpret_cast<const short8*>(bp0 + ka);
          short8 bv1 = *reinterpret_cast<const short8*>(bp1 + ka);
          a00 = __builtin_amdgcn_mfma_f32_16x16x32_bf16(av0, bv0, a00, 0, 0, 0);
          a01 = __builtin_amdgcn_mfma_f32_16x16x32_bf16(av0, bv1, a01, 0, 0, 0);
          a10 = __builtin_amdgcn_mfma_f32_16x16x32_bf16(av1, bv0, a10, 0, 0, 0);
          a11 = __builtin_amdgcn_mfma_f32_16x16x32_bf16(av1, bv1, a11, 0, 0, 0);
        }
      }
    }

    // psum -> LDS exchange (C layout: row = (l>>4)*4+q, col = l&15)
    #pragma unroll
    for (int q = 0; q < 4; ++q) {
      ex[w][ 0 + (l >> 4) * 4 + q][ 0 + (l & 15)] = a00[q];
      ex[w][ 0 + (l >> 4) * 4 + q][16 + (l & 15)] = a01[q];
      ex[w][16 + (l >> 4) * 4 + q][ 0 + (l & 15)] = a10[q];
      ex[w][16 + (l >> 4) * 4 + q][16 + (l & 15)] = a11[q];
    }
    __syncthreads();

    float pI = bI, pF = bF, pO = bO, pG = bG;
    #pragma unroll
    for (int wv = 0; wv < 4; ++wv) {
      pI += ex[wv][nE][ 0 + jj];
      pF += ex[wv][nE][ 8 + jj];
      pO += ex[wv][nE][16 + jj];
      pG += ex[wv][nE][24 + jj];
    }
    const float ig = sigm(pI), fg = sigm(pF), og = sigm(pO);
    const float gg = tanhfast(pG);
    c_reg = fg * c_reg + ig * gg;
    const float hv = og * tanhfast(c_reg);

    out[((size_t)(n0 + nE) * Tt + t) * Hh + jc0 + jj] = hv;
    hbn[nE * Hh + jc0 + jj] = f2b(hv);

    if (t + 1 < Tt)
      team_barrier(tArr, tRel, r, slot, tid, (unsigned)(t + 2));
  }
}

extern "C" void kernel_launch(void* const* d_in, const int* in_sizes, int n_in,
                              void* d_out, int out_size, void* d_ws, size_t ws_size,
                              hipStream_t stream) {
  const float* x    = (const float*)d_in[0];
  const float* h0   = (const float*)d_in[1];
  const float* Wx   = (const float*)d_in[2];
  const float* Wh   = (const float*)d_in[3];
  const float* bias = (const float*)d_in[4];
  float* out = (float*)d_out;

  char* wsb = (char*)d_ws;
  Flag* arr  = (Flag*)wsb;                         // 2*128 lines = 32 KiB
  Flag* rel  = (Flag*)(wsb + 32768);               // 2*4 lines = 1 KiB
  u16*  hbase = (u16*)(wsb + 65536);               // 2 teams x 2 x 32 x 1024 bf16 = 256 KiB
  const size_t xb_off = (size_t)1 << 20;
  const size_t xb_bytes = (size_t)Nb * Tt * Dd * 2;
  u16* xb = (u16*)(wsb + xb_off);

  hipMemsetAsync(wsb, 0, 40960, stream);           // clear flags each launch

  const bool use_xb = ws_size >= xb_off + xb_bytes;
  void* args[] = {(void*)&x, (void*)&xb, (void*)&h0, (void*)&Wx, (void*)&Wh,
                  (void*)&bias, (void*)&out, (void*)&hbase, (void*)&arr, (void*)&rel};
  if (use_xb) {
    cvt_x_kernel<<<dim3((Nb * Tt * Dd) / (8 * TPB)), dim3(TPB), 0, stream>>>(x, xb);
    hipLaunchCooperativeKernel((const void*)lstm_team<true>,
                               dim3(NWG), dim3(TPB), args, 0, stream);
  } else {
    hipLaunchCooperativeKernel((const void*)lstm_team<false>,
                               dim3(NWG), dim3(TPB), args, 0, stream);
  }
}

// Round 3
// 11502.522 us; speedup vs baseline: 3.3332x; 2.3464x over previous
//
#include <hip/hip_runtime.h>

typedef unsigned short u16;
typedef unsigned long long u64;
typedef __attribute__((ext_vector_type(8))) short short8;
typedef __attribute__((ext_vector_type(4))) float f32x4;

#define DEVINL __device__ __forceinline__

constexpr int Nb = 64;     // batch
constexpr int Tt = 1024;   // time
constexpr int Dd = 1024;   // input dim
constexpr int Hh = 1024;   // hidden
constexpr int NWG = 256;   // workgroups (== CUs)
constexpr int TPB = 256;   // threads per wg (4 waves)
constexpr int TWG = 128;   // wgs per team
constexpr int MS  = 32;    // samples per team

struct Flag { unsigned v; unsigned pad[31]; };  // one 128B line each

DEVINL u16 f2b(float f) {
  union { float f; unsigned u; } v; v.f = f;
  unsigned r = (v.u + 0x7fffu + ((v.u >> 16) & 1u)) >> 16;
  return (u16)r;
}
DEVINL float sigm(float x) { return 1.f / (1.f + __expf(-x)); }
DEVINL float tanhfast(float x) { float e = __expf(2.f * x); return 1.f - 2.f / (e + 1.f); }

// Device-scope (IC-coherent) h-fragment load: 2x relaxed u64 atomic loads.
// Relaxed agent atomics bypass L1/L2 (SC1) -> always read current IC data;
// no acquire fence => no L2 invalidate. Compiler tracks these loads and
// schedules/waitcnts them like normal loads.
DEVINL short8 ldh16(const u16* p) {
  u64 a = __hip_atomic_load((const u64*)p,       __ATOMIC_RELAXED, __HIP_MEMORY_SCOPE_AGENT);
  u64 b = __hip_atomic_load((const u64*)(p + 4), __ATOMIC_RELAXED, __HIP_MEMORY_SCOPE_AGENT);
  union { u64 q[2]; short8 v; } u;
  u.q[0] = a; u.q[1] = b;
  return u.v;
}

__global__ void cvt_x_kernel(const float* __restrict__ x, u16* __restrict__ xb) {
  size_t i = ((size_t)blockIdx.x * TPB + threadIdx.x) * 8;
  float4 a = *reinterpret_cast<const float4*>(x + i);
  float4 b = *reinterpret_cast<const float4*>(x + i + 4);
  short8 r;
  r[0] = (short)f2b(a.x); r[1] = (short)f2b(a.y);
  r[2] = (short)f2b(a.z); r[3] = (short)f2b(a.w);
  r[4] = (short)f2b(b.x); r[5] = (short)f2b(b.y);
  r[6] = (short)f2b(b.z); r[7] = (short)f2b(b.w);
  *reinterpret_cast<short8*>(xb + i) = r;
}

// 2 independent teams x 128 wgs; team owns 32 samples, wg owns 8 h-cols.
// [Wh;Wx] slice [32][2048] bf16 LDS-resident (XOR-swizzled). h exchange +
// flags use ONLY relaxed agent atomics (IC-coherent, no cache-maintenance
// fences). Per step: x-MFMA (waves 2/3) -> poll flags -> h-MFMA (waves 0/1)
// -> LDS reduce -> gates -> h atomic stores -> vmcnt(0) -> flag store.
template<bool XBF16>
__global__ __launch_bounds__(TPB, 1) void lstm_team(
    const float* __restrict__ x, const u16* __restrict__ xb,
    const float* __restrict__ h0, const float* __restrict__ Wx,
    const float* __restrict__ Wh, const float* __restrict__ bias,
    float* __restrict__ out, u16* __restrict__ hbase,
    Flag* __restrict__ arr)
{
  __shared__ u16 Bt[32][2048];       // 128 KiB, [c][k ^ ((c&7)<<3)]
  __shared__ float ex[4][32][36];    // 18 KiB partial-sum exchange
  __shared__ u16 hstage[32][8];      // h repack for u64 stores

  const int g   = blockIdx.x;
  const int tid = threadIdx.x;
  const int w   = tid >> 6;
  const int l   = tid & 63;

  const int team = ((g & 7) < 4) ? 0 : 1;
  const int r    = (g >> 3) * 4 + (g & 3);  // rank in team, 0..127
  const int n0   = team * MS;
  const int jc0  = r * 8;                   // this wg's 8 h-columns

  Flag* tArr = arr + team * TWG;
  u16*  hb0  = hbase + (size_t)team * (2 * MS * Hh);

  // ---- one-time: [Wh;Wx] column slice -> LDS bf16, swizzled ----
  for (int idx = tid; idx < 32 * 2048; idx += TPB) {
    int k = idx >> 5;
    int c = idx & 31;
    int pc = (c >> 3) * 1024 + jc0 + (c & 7);
    float v = (k < 1024) ? Wh[(size_t)k * 4096 + pc]
                         : Wx[(size_t)(k - 1024) * 4096 + pc];
    Bt[c][k ^ ((c & 7) << 3)] = f2b(v);
  }

  // ---- one-time: h0 -> ping slot 0 via device-scope u64 stores ----
  if (tid < 64) {
    int v0 = r * 256 + tid * 4;  // team-flat h index, this wg's 256-slice
    const float* hp = h0 + (size_t)n0 * Hh + v0;
    u64 pk = (u64)f2b(hp[0]) | ((u64)f2b(hp[1]) << 16) |
             ((u64)f2b(hp[2]) << 32) | ((u64)f2b(hp[3]) << 48);
    __hip_atomic_store((u64*)(hb0 + v0), pk, __ATOMIC_RELAXED, __HIP_MEMORY_SCOPE_AGENT);
    asm volatile("s_waitcnt vmcnt(0)" ::: "memory");
    if (tid == 0)
      __hip_atomic_store(&tArr[r].v, 1u, __ATOMIC_RELAXED, __HIP_MEMORY_SCOPE_AGENT);
  }
  __syncthreads();  // Bt ready

  // epilogue roles: thread -> (nE = tid>>3, jj = tid&7)
  const int jj = tid & 7;
  const int nE = tid >> 3;
  const float bI = bias[0 * 1024 + jc0 + jj];
  const float bF = bias[1 * 1024 + jc0 + jj];
  const float bO = bias[2 * 1024 + jc0 + jj];
  const float bG = bias[3 * 1024 + jc0 + jj];
  float c_reg = 0.f;

  // MFMA lane roles
  const int arow = l & 15;
  const int kg   = (l >> 4) * 8;
  const int kb   = w * 512;         // wave's K-slice base (abs k in [Wh;Wx])
  const int sw   = (l & 7) << 3;
  const u16* bp0 = &Bt[l & 15][0];
  const u16* bp1 = &Bt[16 | (l & 15)][0];

  for (int t = 0; t < Tt; ++t) {
    const u16* hb  = hb0 + (t & 1) * (MS * Hh);
    u16*       hbn = hb0 + ((t + 1) & 1) * (MS * Hh);

    f32x4 a00 = {0.f,0.f,0.f,0.f}, a01 = {0.f,0.f,0.f,0.f};
    f32x4 a10 = {0.f,0.f,0.f,0.f}, a11 = {0.f,0.f,0.f,0.f};

    // ---- phase A: x contribution (waves 2/3) — independent of h_t,
    //      overlaps the flag wait below ----
    if (w >= 2) {
      const int d0 = kb - 1024 + kg;
      if constexpr (XBF16) {
        const u16* ap0 = xb + ((size_t)(n0 + arow)      * Tt + t) * Dd + d0;
        const u16* ap1 = xb + ((size_t)(n0 + 16 + arow) * Tt + t) * Dd + d0;
        #pragma unroll
        for (int kk = 0; kk < 512; kk += 32) {
          short8 av0 = *reinterpret_cast<const short8*>(ap0 + kk);
          short8 av1 = *reinterpret_cast<const short8*>(ap1 + kk);
          int ka = (kb + kg + kk) ^ sw;
          short8 bv0 = *reinterpret_cast<const short8*>(bp0 + ka);
          short8 bv1 = *reinterpret_cast<const short8*>(bp1 + ka);
          a00 = __builtin_amdgcn_mfma_f32_16x16x32_bf16(av0, bv0, a00, 0, 0, 0);
          a01 = __builtin_amdgcn_mfma_f32_16x16x32_bf16(av0, bv1, a01, 0, 0, 0);
          a10 = __builtin_amdgcn_mfma_f32_16x16x32_bf16(av1, bv0, a10, 0, 0, 0);
          a11 = __builtin_amdgcn_mfma_f32_16x16x32_bf16(av1, bv1, a11, 0, 0, 0);
        }
      } else {
        const float* ap0 = x + ((size_t)(n0 + arow)      * Tt + t) * Dd + d0;
        const float* ap1 = x + ((size_t)(n0 + 16 + arow) * Tt + t) * Dd + d0;
        #pragma unroll
        for (int kk = 0; kk < 512; kk += 32) {
          float4 xa = *reinterpret_cast<const float4*>(ap0 + kk);
          float4 xc = *reinterpret_cast<const float4*>(ap0 + kk + 4);
          float4 ya = *reinterpret_cast<const float4*>(ap1 + kk);
          float4 yc = *reinterpret_cast<const float4*>(ap1 + kk + 4);
          short8 av0, av1;
          av0[0]=(short)f2b(xa.x); av0[1]=(short)f2b(xa.y);
          av0[2]=(short)f2b(xa.z); av0[3]=(short)f2b(xa.w);
          av0[4]=(short)f2b(xc.x); av0[5]=(short)f2b(xc.y);
          av0[6]=(short)f2b(xc.z); av0[7]=(short)f2b(xc.w);
          av1[0]=(short)f2b(ya.x); av1[1]=(short)f2b(ya.y);
          av1[2]=(short)f2b(ya.z); av1[3]=(short)f2b(ya.w);
          av1[4]=(short)f2b(yc.x); av1[5]=(short)f2b(yc.y);
          av1[6]=(short)f2b(yc.z); av1[7]=(short)f2b(yc.w);
          int ka = (kb + kg + kk) ^ sw;
          short8 bv0 = *reinterpret_cast<const short8*>(bp0 + ka);
          short8 bv1 = *reinterpret_cast<const short8*>(bp1 + ka);
          a00 = __builtin_amdgcn_mfma_f32_16x16x32_bf16(av0, bv0, a00, 0, 0, 0);
          a01 = __builtin_amdgcn_mfma_f32_16x16x32_bf16(av0, bv1, a01, 0, 0, 0);
          a10 = __builtin_amdgcn_mfma_f32_16x16x32_bf16(av1, bv0, a10, 0, 0, 0);
          a11 = __builtin_amdgcn_mfma_f32_16x16x32_bf16(av1, bv1, a11, 0, 0, 0);
        }
      }
    }

    // ---- phase B: wait for h_t (epoch t+1); waves 0/1 poll in parallel ----
    if (tid < TWG) {
      while (__hip_atomic_load(&tArr[tid].v, __ATOMIC_RELAXED,
                               __HIP_MEMORY_SCOPE_AGENT) < (unsigned)(t + 1))
        __builtin_amdgcn_s_sleep(2);
    }
    __syncthreads();

    // ---- phase C: h contribution (waves 0/1), IC-coherent loads ----
    if (w < 2) {
      const u16* ap = hb + (size_t)arow * Hh + kb + kg;
      #pragma unroll
      for (int kk = 0; kk < 512; kk += 32) {
        short8 av0 = ldh16(ap + kk);
        short8 av1 = ldh16(ap + 16 * Hh + kk);
        int ka = (kb + kg + kk) ^ sw;
        short8 bv0 = *reinterpret_cast<const short8*>(bp0 + ka);
        short8 bv1 = *reinterpret_cast<const short8*>(bp1 + ka);
        a00 = __builtin_amdgcn_mfma_f32_16x16x32_bf16(av0, bv0, a00, 0, 0, 0);
        a01 = __builtin_amdgcn_mfma_f32_16x16x32_bf16(av0, bv1, a01, 0, 0, 0);
        a10 = __builtin_amdgcn_mfma_f32_16x16x32_bf16(av1, bv0, a10, 0, 0, 0);
        a11 = __builtin_amdgcn_mfma_f32_16x16x32_bf16(av1, bv1, a11, 0, 0, 0);
      }
    }

    // ---- phase D: partial sums -> LDS ----
    #pragma unroll
    for (int q = 0; q < 4; ++q) {
      ex[w][ 0 + (l >> 4) * 4 + q][ 0 + (l & 15)] = a00[q];
      ex[w][ 0 + (l >> 4) * 4 + q][16 + (l & 15)] = a01[q];
      ex[w][16 + (l >> 4) * 4 + q][ 0 + (l & 15)] = a10[q];
      ex[w][16 + (l >> 4) * 4 + q][16 + (l & 15)] = a11[q];
    }
    __syncthreads();

    // ---- phase E: gates, state update ----
    float pI = bI, pF = bF, pO = bO, pG = bG;
    #pragma unroll
    for (int wv = 0; wv < 4; ++wv) {
      pI += ex[wv][nE][ 0 + jj];
      pF += ex[wv][nE][ 8 + jj];
      pO += ex[wv][nE][16 + jj];
      pG += ex[wv][nE][24 + jj];
    }
    const float ig = sigm(pI), fg = sigm(pF), og = sigm(pO);
    const float gg = tanhfast(pG);
    c_reg = fg * c_reg + ig * gg;
    const float hv = og * tanhfast(c_reg);

    hstage[nE][jj] = f2b(hv);
    __syncthreads();

    // wave0: pack + device-scope h store, drain, then flag. out-stores are
    // issued AFTER the flag path so they don't sit in wave0's vmcnt.
    if (tid < 64) {
      int n  = tid >> 1;
      int jc = (tid & 1) * 4;
      u64 pk = *reinterpret_cast<const u64*>(&hstage[n][jc]);
      __hip_atomic_store((u64*)(hbn + n * Hh + jc0 + jc), pk,
                         __ATOMIC_RELAXED, __HIP_MEMORY_SCOPE_AGENT);
      asm volatile("s_waitcnt vmcnt(0)" ::: "memory");
      if (tid == 0 && t + 1 < Tt)
        __hip_atomic_store(&tArr[r].v, (unsigned)(t + 2),
                           __ATOMIC_RELAXED, __HIP_MEMORY_SCOPE_AGENT);
    }
    out[((size_t)(n0 + nE) * Tt + t) * Hh + jc0 + jj] = hv;
  }
}

extern "C" void kernel_launch(void* const* d_in, const int* in_sizes, int n_in,
                              void* d_out, int out_size, void* d_ws, size_t ws_size,
                              hipStream_t stream) {
  const float* x    = (const float*)d_in[0];
  const float* h0   = (const float*)d_in[1];
  const float* Wx   = (const float*)d_in[2];
  const float* Wh   = (const float*)d_in[3];
  const float* bias = (const float*)d_in[4];
  float* out = (float*)d_out;

  char* wsb = (char*)d_ws;
  Flag* arr   = (Flag*)wsb;                        // 2*128 lines = 32 KiB
  u16*  hbase = (u16*)(wsb + 65536);               // 2 teams x 2 x 32 x 1024 bf16
  const size_t xb_off = (size_t)1 << 20;
  const size_t xb_bytes = (size_t)Nb * Tt * Dd * 2;
  u16* xb = (u16*)(wsb + xb_off);

  hipMemsetAsync(wsb, 0, 40960, stream);           // clear flags each launch

  const bool use_xb = ws_size >= xb_off + xb_bytes;
  void* args[] = {(void*)&x, (void*)&xb, (void*)&h0, (void*)&Wx, (void*)&Wh,
                  (void*)&bias, (void*)&out, (void*)&hbase, (void*)&arr};
  if (use_xb) {
    cvt_x_kernel<<<dim3((Nb * Tt * Dd) / (8 * TPB)), dim3(TPB), 0, stream>>>(x, xb);
    hipLaunchCooperativeKernel((const void*)lstm_team<true>,
                               dim3(NWG), dim3(TPB), args, 0, stream);
  } else {
    hipLaunchCooperativeKernel((const void*)lstm_team<false>,
                               dim3(NWG), dim3(TPB), args, 0, stream);
  }
}